// Round 2
// baseline (761.040 us; speedup 1.0000x reference)
//
#include <hip/hip_runtime.h>
#include <hip/hip_bf16.h>
#include <math.h>

#define NN     50000
#define FIN    128
#define F1     64      // H1*C1 = layer-1 output features
#define NH1    8
#define F2     64      // layer-2 output features

// ---------------- runtime dtype helpers ----------------
// flags[0] = 1 if float tensors are fp32 (else bf16)
// flags[1] = 1 if edge_index is int64 (else int32)

__device__ __forceinline__ float loadF(const void* p, long long i, int fp32) {
    if (fp32) return ((const float*)p)[i];
    return __bfloat162float(((const __hip_bfloat16*)p)[i]);
}
__device__ __forceinline__ int loadI(const void* p, long long i, int i64) {
    if (i64) return (int)((const long long*)p)[i];
    return ((const int*)p)[i];
}

__global__ void k_sniff(const void* x, const void* ei, int* flags) {
    __shared__ int s_nanexp, s_oddnz;
    if (threadIdx.x == 0) { s_nanexp = 0; s_oddnz = 0; }
    __syncthreads();
    const unsigned short* u = (const unsigned short*)x;
    int cnt = 0;
    for (int i = threadIdx.x; i < 32768; i += 256) {
        unsigned short v = u[i];
        if ((v & 0x7F80) == 0x7F80) cnt++;         // bf16 Inf/NaN bit pattern
    }
    if (cnt) atomicAdd(&s_nanexp, cnt);
    const unsigned* e32 = (const unsigned*)ei;
    int nz = 0;
    for (int i = threadIdx.x; i < 4096; i += 256) {
        if (e32[2 * i + 1] != 0u) nz++;            // high words if int64
    }
    if (nz) atomicAdd(&s_oddnz, nz);
    __syncthreads();
    if (threadIdx.x == 0) {
        flags[0] = (s_nanexp > 4) ? 1 : 0;         // fp32 floats
        flags[1] = (s_oddnz == 0) ? 1 : 0;         // int64 edges
    }
}

// ---------------- CSR build ----------------

__global__ void k_count(const void* __restrict__ ei, int E, int Etot,
                        int* __restrict__ deg, const int* __restrict__ flags) {
    int i64 = flags[1];
    int j = blockIdx.x * blockDim.x + threadIdx.x;
    if (j >= Etot) return;
    int d = (j < E) ? loadI(ei, (long long)E + j, i64) : (j - E);
    if ((unsigned)d < NN) atomicAdd(&deg[d], 1);
}

__global__ void k_scan_a(const int* __restrict__ deg, int* __restrict__ offs,
                         int* __restrict__ bsum, int n) {
    __shared__ int sd[512];
    int tid = threadIdx.x;
    int i = blockIdx.x * 512 + tid;
    int v = (i < n) ? deg[i] : 0;
    sd[tid] = v;
    __syncthreads();
    for (int off = 1; off < 512; off <<= 1) {
        int t = (tid >= off) ? sd[tid - off] : 0;
        __syncthreads();
        sd[tid] += t;
        __syncthreads();
    }
    if (i < n) offs[i] = sd[tid] - v;               // exclusive within block
    if (tid == 511) bsum[blockIdx.x] = sd[511];     // block total
}

__global__ void k_scan_b(int* __restrict__ bsum, int nb) {
    if (threadIdx.x == 0 && blockIdx.x == 0) {
        int run = 0;
        for (int b = 0; b < nb; ++b) { int t = bsum[b]; bsum[b] = run; run += t; }
    }
}

__global__ void k_scan_c(int* __restrict__ offs, int* __restrict__ next,
                         const int* __restrict__ bsum, int n, int Etot) {
    int i = blockIdx.x * 512 + threadIdx.x;
    if (i < n) {
        int v = offs[i] + bsum[blockIdx.x];
        offs[i] = v;
        next[i] = v;                                 // scatter cursor
    }
    if (i == 0) offs[n] = Etot;
}

__global__ void k_scatter(const void* __restrict__ ei, int E, int Etot,
                          int* __restrict__ next, int* __restrict__ perm,
                          const int* __restrict__ flags) {
    int i64 = flags[1];
    int j = blockIdx.x * blockDim.x + threadIdx.x;
    if (j >= Etot) return;
    int s, d;
    if (j < E) { s = loadI(ei, j, i64); d = loadI(ei, (long long)E + j, i64); }
    else       { s = d = j - E; }
    if ((unsigned)d >= NN || (unsigned)s >= NN) return;
    int pos = atomicAdd(&next[d], 1);
    perm[pos] = s;
}

// ---------------- Layer 1 GEMM + attention coefficients ----------------
// 256 threads = 4 waves; each wave computes 4 nodes (16 nodes/block).

__global__ __launch_bounds__(256) void k_gemm1(
    const void* __restrict__ x, const void* __restrict__ W1,
    const void* __restrict__ attS, const void* __restrict__ attD,
    __hip_bfloat16* __restrict__ h1, float* __restrict__ a1s,
    float* __restrict__ a1d, int n, const int* __restrict__ flags) {
    int fp32 = flags[0];
    __shared__ float Wl[FIN * F1];   // 32 KB
    __shared__ float xl[16 * FIN];   // 8 KB
    int tid = threadIdx.x;
    for (int i = tid; i < FIN * F1; i += 256) Wl[i] = loadF(W1, i, fp32);
    int n0 = blockIdx.x * 16;
    for (int i = tid; i < 16 * FIN; i += 256) {
        int node = n0 + i / FIN;
        xl[i] = (node < n) ? loadF(x, (long long)node * FIN + (i % FIN), fp32) : 0.f;
    }
    __syncthreads();
    int w = tid >> 6, c = tid & 63;
    float aS = loadF(attS, c, fp32);
    float aD = loadF(attD, c, fp32);
    float acc[4] = {0.f, 0.f, 0.f, 0.f};
    int base = w * 4;
    for (int k = 0; k < FIN; ++k) {
        float wv = Wl[k * F1 + c];
        acc[0] += xl[(base + 0) * FIN + k] * wv;
        acc[1] += xl[(base + 1) * FIN + k] * wv;
        acc[2] += xl[(base + 2) * FIN + k] * wv;
        acc[3] += xl[(base + 3) * FIN + k] * wv;
    }
    for (int m = 0; m < 4; ++m) {
        int node = n0 + base + m;
        if (node >= n) break;
        float v = acc[m];
        h1[node * F1 + c] = __float2bfloat16(v);
        float ps = v * aS, pd = v * aD;
        for (int off = 1; off < 8; off <<= 1) {
            ps += __shfl_xor(ps, off, 64);
            pd += __shfl_xor(pd, off, 64);
        }
        if ((c & 7) == 0) {
            a1s[node * NH1 + (c >> 3)] = ps;
            a1d[node * NH1 + (c >> 3)] = pd;
        }
    }
}

// ---------------- Layer 1 aggregation (fused softmax, no segment-max) ----------------

__global__ __launch_bounds__(256) void k_agg1(
    const int* __restrict__ offs, const int* __restrict__ perm,
    const __hip_bfloat16* __restrict__ h1, const float* __restrict__ a1s,
    const float* __restrict__ a1d, const void* __restrict__ b1,
    __hip_bfloat16* __restrict__ helu, int n, const int* __restrict__ flags) {
    int fp32 = flags[0];
    int w = threadIdx.x >> 6, c = threadIdx.x & 63;
    int d = blockIdx.x * 4 + w;
    if (d >= n) return;
    int start = offs[d], end = offs[d + 1];
    float ad = a1d[d * NH1 + (c >> 3)];
    float acc = 0.f, den = 0.f;
    for (int i = start; i < end; ++i) {
        int s = perm[i];
        float e = a1s[s * NH1 + (c >> 3)] + ad;
        e = (e > 0.f) ? e : 0.2f * e;            // leaky_relu(0.2)
        float p = __expf(e);
        acc += p * __bfloat162float(h1[s * F1 + c]);
        den += p;
    }
    float v = acc / (den + 1e-16f) + loadF(b1, c, fp32);
    v = (v > 0.f) ? v : expm1f(v);               // ELU
    helu[d * F1 + c] = __float2bfloat16(v);
}

// ---------------- Layer 2 GEMM + attention coefficients ----------------

__global__ __launch_bounds__(256) void k_gemm2(
    const __hip_bfloat16* __restrict__ helu, const void* __restrict__ W2,
    const void* __restrict__ attS, const void* __restrict__ attD,
    __hip_bfloat16* __restrict__ h2, float* __restrict__ a2s,
    float* __restrict__ a2d, int n, const int* __restrict__ flags) {
    int fp32 = flags[0];
    __shared__ float Wl[F1 * F2];    // 16 KB
    __shared__ float hl[16 * F1];    // 4 KB
    int tid = threadIdx.x;
    for (int i = tid; i < F1 * F2; i += 256) Wl[i] = loadF(W2, i, fp32);
    int n0 = blockIdx.x * 16;
    for (int i = tid; i < 16 * F1; i += 256) {
        int node = n0 + i / F1;
        hl[i] = (node < n) ? __bfloat162float(helu[node * F1 + (i % F1)]) : 0.f;
    }
    __syncthreads();
    int w = tid >> 6, c = tid & 63;
    float aS = loadF(attS, c, fp32);
    float aD = loadF(attD, c, fp32);
    float acc[4] = {0.f, 0.f, 0.f, 0.f};
    int base = w * 4;
    for (int k = 0; k < F1; ++k) {
        float wv = Wl[k * F2 + c];
        acc[0] += hl[(base + 0) * F1 + k] * wv;
        acc[1] += hl[(base + 1) * F1 + k] * wv;
        acc[2] += hl[(base + 2) * F1 + k] * wv;
        acc[3] += hl[(base + 3) * F1 + k] * wv;
    }
    for (int m = 0; m < 4; ++m) {
        int node = n0 + base + m;
        if (node >= n) break;
        float v = acc[m];
        h2[node * F2 + c] = __float2bfloat16(v);
        float ps = v * aS, pd = v * aD;
        for (int off = 1; off < 64; off <<= 1) {
            ps += __shfl_xor(ps, off, 64);
            pd += __shfl_xor(pd, off, 64);
        }
        if (c == 0) { a2s[node] = ps; a2d[node] = pd; }
    }
}

// ---------------- Layer 2 aggregation + final linear ----------------

__global__ __launch_bounds__(256) void k_agg2(
    const int* __restrict__ offs, const int* __restrict__ perm,
    const __hip_bfloat16* __restrict__ h2, const float* __restrict__ a2s,
    const float* __restrict__ a2d, const void* __restrict__ b2,
    const void* __restrict__ linW, const void* __restrict__ linb,
    void* __restrict__ out, int n, const int* __restrict__ flags) {
    int fp32 = flags[0];
    int w = threadIdx.x >> 6, c = threadIdx.x & 63;
    int d = blockIdx.x * 4 + w;
    if (d >= n) return;
    int start = offs[d], end = offs[d + 1];
    float ad = a2d[d];
    float acc = 0.f, den = 0.f;
    for (int i = start; i < end; ++i) {
        int s = perm[i];
        float e = a2s[s] + ad;
        e = (e > 0.f) ? e : 0.2f * e;
        float p = __expf(e);
        acc += p * __bfloat162float(h2[s * F2 + c]);
        den += p;
    }
    float v = acc / (den + 1e-16f) + loadF(b2, c, fp32);
    float part = v * loadF(linW, c, fp32);
    for (int off = 1; off < 64; off <<= 1) part += __shfl_xor(part, off, 64);
    if (c == 0) {
        float r = part + loadF(linb, 0, fp32);
        if (fp32) ((float*)out)[d] = r;
        else      ((__hip_bfloat16*)out)[d] = __float2bfloat16(r);
    }
}

// ---------------- host launcher ----------------

static inline char* carve(char*& p, size_t bytes) {
    char* r = p;
    p += (bytes + 255) & ~size_t(255);
    return r;
}

extern "C" void kernel_launch(void* const* d_in, const int* in_sizes, int n_in,
                              void* d_out, int out_size, void* d_ws, size_t ws_size,
                              hipStream_t stream) {
    const void* x     = d_in[0];
    const void* ei    = d_in[1];
    const void* W1    = d_in[2];
    const void* attS1 = d_in[3];
    const void* attD1 = d_in[4];
    const void* b1    = d_in[5];
    const void* W2    = d_in[6];
    const void* attS2 = d_in[7];
    const void* attD2 = d_in[8];
    const void* b2    = d_in[9];
    const void* linW  = d_in[10];
    const void* linb  = d_in[11];

    int E    = in_sizes[1] / 2;
    int Etot = E + NN;

    // workspace layout (~23 MB total)
    char* p = (char*)d_ws;
    int*   flags = (int*)carve(p, 256);
    int*   deg   = (int*)carve(p, (size_t)NN * 4);
    int*   offs  = (int*)carve(p, (size_t)(NN + 1) * 4);
    int*   next  = (int*)carve(p, (size_t)NN * 4);
    int*   bsum  = (int*)carve(p, 512 * 4);
    int*   perm  = (int*)carve(p, (size_t)Etot * 4);
    float* a1s   = (float*)carve(p, (size_t)NN * NH1 * 4);   // reused as a2s
    float* a1d   = (float*)carve(p, (size_t)NN * NH1 * 4);   // reused as a2d
    __hip_bfloat16* h1   = (__hip_bfloat16*)carve(p, (size_t)NN * F1 * 2); // reused as h2
    __hip_bfloat16* helu = (__hip_bfloat16*)carve(p, (size_t)NN * F1 * 2);
    float* a2s = a1s;
    float* a2d = a1d;
    __hip_bfloat16* h2 = h1;

    hipMemsetAsync(deg, 0, (size_t)NN * 4, stream);
    k_sniff<<<1, 256, 0, stream>>>(x, ei, flags);

    int eb = (Etot + 255) / 256;
    k_count<<<eb, 256, 0, stream>>>(ei, E, Etot, deg, flags);
    int nb = (NN + 511) / 512;
    k_scan_a<<<nb, 512, 0, stream>>>(deg, offs, bsum, NN);
    k_scan_b<<<1, 64, 0, stream>>>(bsum, nb);
    k_scan_c<<<nb, 512, 0, stream>>>(offs, next, bsum, NN, Etot);
    k_scatter<<<eb, 256, 0, stream>>>(ei, E, Etot, next, perm, flags);

    k_gemm1<<<(NN + 15) / 16, 256, 0, stream>>>(x, W1, attS1, attD1, h1, a1s, a1d, NN, flags);
    k_agg1<<<(NN + 3) / 4, 256, 0, stream>>>(offs, perm, h1, a1s, a1d, b1, helu, NN, flags);
    k_gemm2<<<(NN + 15) / 16, 256, 0, stream>>>(helu, W2, attS2, attD2, h2, a2s, a2d, NN, flags);
    k_agg2<<<(NN + 3) / 4, 256, 0, stream>>>(offs, perm, h2, a2s, a2d, b2, linW, linb, d_out, NN, flags);
}

// Round 3
// 529.566 us; speedup vs baseline: 1.4371x; 1.4371x over previous
//
#include <hip/hip_runtime.h>
#include <hip/hip_bf16.h>
#include <math.h>

#define NN     50000
#define FIN    128
#define F1     64      // H1*C1 = layer-1 output features
#define NH1    8
#define F2     64      // layer-2 output features

// ---------------- runtime dtype helpers ----------------
// flags[0] = 1 if float tensors are fp32 (else bf16)
// flags[1] = 1 if edge_index is int64 (else int32)

__device__ __forceinline__ float loadF(const void* p, long long i, int fp32) {
    if (fp32) return ((const float*)p)[i];
    return __bfloat162float(((const __hip_bfloat16*)p)[i]);
}
__device__ __forceinline__ int loadI(const void* p, long long i, int i64) {
    if (i64) return (int)((const long long*)p)[i];
    return ((const int*)p)[i];
}

__global__ void k_sniff(const void* x, const void* ei, int* flags) {
    __shared__ int s_nanexp, s_oddnz;
    if (threadIdx.x == 0) { s_nanexp = 0; s_oddnz = 0; }
    __syncthreads();
    const unsigned short* u = (const unsigned short*)x;
    int cnt = 0;
    for (int i = threadIdx.x; i < 32768; i += 256) {
        unsigned short v = u[i];
        if ((v & 0x7F80) == 0x7F80) cnt++;         // bf16 Inf/NaN bit pattern
    }
    if (cnt) atomicAdd(&s_nanexp, cnt);
    const unsigned* e32 = (const unsigned*)ei;
    int nz = 0;
    for (int i = threadIdx.x; i < 4096; i += 256) {
        if (e32[2 * i + 1] != 0u) nz++;            // high words if int64
    }
    if (nz) atomicAdd(&s_oddnz, nz);
    __syncthreads();
    if (threadIdx.x == 0) {
        flags[0] = (s_nanexp > 4) ? 1 : 0;         // fp32 floats
        flags[1] = (s_oddnz == 0) ? 1 : 0;         // int64 edges
    }
}

// ---------------- CSR build ----------------

__global__ void k_count(const void* __restrict__ ei, int E, int Etot,
                        int* __restrict__ deg, const int* __restrict__ flags) {
    int i64 = flags[1];
    int j = blockIdx.x * blockDim.x + threadIdx.x;
    if (j >= Etot) return;
    int d = (j < E) ? loadI(ei, (long long)E + j, i64) : (j - E);
    if ((unsigned)d < NN) atomicAdd(&deg[d], 1);
}

__global__ void k_scan_a(const int* __restrict__ deg, int* __restrict__ offs,
                         int* __restrict__ bsum, int n) {
    __shared__ int sd[512];
    int tid = threadIdx.x;
    int i = blockIdx.x * 512 + tid;
    int v = (i < n) ? deg[i] : 0;
    sd[tid] = v;
    __syncthreads();
    for (int off = 1; off < 512; off <<= 1) {
        int t = (tid >= off) ? sd[tid - off] : 0;
        __syncthreads();
        sd[tid] += t;
        __syncthreads();
    }
    if (i < n) offs[i] = sd[tid] - v;               // exclusive within block
    if (tid == 511) bsum[blockIdx.x] = sd[511];     // block total
}

__global__ void k_scan_b(int* __restrict__ bsum, int nb) {
    if (threadIdx.x == 0 && blockIdx.x == 0) {
        int run = 0;
        for (int b = 0; b < nb; ++b) { int t = bsum[b]; bsum[b] = run; run += t; }
    }
}

__global__ void k_scan_c(int* __restrict__ offs, int* __restrict__ next,
                         const int* __restrict__ bsum, int n, int Etot) {
    int i = blockIdx.x * 512 + threadIdx.x;
    if (i < n) {
        int v = offs[i] + bsum[blockIdx.x];
        offs[i] = v;
        next[i] = v;                                 // scatter cursor
    }
    if (i == 0) offs[n] = Etot;
}

__global__ void k_scatter(const void* __restrict__ ei, int E, int Etot,
                          int* __restrict__ next, int* __restrict__ perm,
                          const int* __restrict__ flags) {
    int i64 = flags[1];
    int j = blockIdx.x * blockDim.x + threadIdx.x;
    if (j >= Etot) return;
    int s, d;
    if (j < E) { s = loadI(ei, j, i64); d = loadI(ei, (long long)E + j, i64); }
    else       { s = d = j - E; }
    if ((unsigned)d >= NN || (unsigned)s >= NN) return;
    int pos = atomicAdd(&next[d], 1);
    perm[pos] = s;
}

// ---------------- Layer 1 GEMM + attention coefficients ----------------
// 256 threads = 4 waves; each wave computes 4 nodes (16 nodes/block).

__global__ __launch_bounds__(256) void k_gemm1(
    const void* __restrict__ x, const void* __restrict__ W1,
    const void* __restrict__ attS, const void* __restrict__ attD,
    __hip_bfloat16* __restrict__ h1, float* __restrict__ a1s,
    float* __restrict__ a1d, int n, const int* __restrict__ flags) {
    int fp32 = flags[0];
    __shared__ float Wl[FIN * F1];   // 32 KB
    __shared__ float xl[16 * FIN];   // 8 KB
    int tid = threadIdx.x;
    for (int i = tid; i < FIN * F1; i += 256) Wl[i] = loadF(W1, i, fp32);
    int n0 = blockIdx.x * 16;
    for (int i = tid; i < 16 * FIN; i += 256) {
        int node = n0 + i / FIN;
        xl[i] = (node < n) ? loadF(x, (long long)node * FIN + (i % FIN), fp32) : 0.f;
    }
    __syncthreads();
    int w = tid >> 6, c = tid & 63;
    float aS = loadF(attS, c, fp32);
    float aD = loadF(attD, c, fp32);
    float acc[4] = {0.f, 0.f, 0.f, 0.f};
    int base = w * 4;
    #pragma unroll 4
    for (int k = 0; k < FIN; ++k) {
        float wv = Wl[k * F1 + c];
        acc[0] += xl[(base + 0) * FIN + k] * wv;
        acc[1] += xl[(base + 1) * FIN + k] * wv;
        acc[2] += xl[(base + 2) * FIN + k] * wv;
        acc[3] += xl[(base + 3) * FIN + k] * wv;
    }
    for (int m = 0; m < 4; ++m) {
        int node = n0 + base + m;
        if (node >= n) break;
        float v = acc[m];
        h1[node * F1 + c] = __float2bfloat16(v);
        float ps = v * aS, pd = v * aD;
        for (int off = 1; off < 8; off <<= 1) {
            ps += __shfl_xor(ps, off, 64);
            pd += __shfl_xor(pd, off, 64);
        }
        if ((c & 7) == 0) {
            a1s[node * NH1 + (c >> 3)] = ps;
            a1d[node * NH1 + (c >> 3)] = pd;
        }
    }
}

// ---------------- Layer 1 aggregation ----------------
// One wave per dst node, lane = channel. Edge loop unrolled x8 so 16 gathers
// are in flight per wave (MLP) instead of 2 — the R2 profile showed this loop
// latency-bound (VALUBusy 34%, HBM 7%).

#define UNR 8

__global__ __launch_bounds__(256) void k_agg1(
    const int* __restrict__ offs, const int* __restrict__ perm,
    const __hip_bfloat16* __restrict__ h1, const float* __restrict__ a1s,
    const float* __restrict__ a1d, const void* __restrict__ b1,
    __hip_bfloat16* __restrict__ helu, int n, const int* __restrict__ flags) {
    int fp32 = flags[0];
    int w = threadIdx.x >> 6, c = threadIdx.x & 63;
    int d = blockIdx.x * 4 + w;
    if (d >= n) return;
    int start = offs[d], end = offs[d + 1];
    int hidx = c >> 3;
    float ad = a1d[d * NH1 + hidx];
    float acc = 0.f, den = 0.f;
    const unsigned short* hu = (const unsigned short*)h1;
    int i = start;
    for (; i + UNR <= end; i += UNR) {
        int ss[UNR];
        #pragma unroll
        for (int u = 0; u < UNR; ++u) ss[u] = perm[i + u];
        float ee[UNR];
        unsigned short hh[UNR];
        #pragma unroll
        for (int u = 0; u < UNR; ++u) ee[u] = a1s[ss[u] * NH1 + hidx];
        #pragma unroll
        for (int u = 0; u < UNR; ++u) hh[u] = hu[ss[u] * F1 + c];
        #pragma unroll
        for (int u = 0; u < UNR; ++u) {
            float e = ee[u] + ad;
            e = (e > 0.f) ? e : 0.2f * e;            // leaky_relu(0.2)
            float p = __expf(e);
            unsigned hb = ((unsigned)hh[u]) << 16;
            acc += p * __uint_as_float(hb);
            den += p;
        }
    }
    for (; i < end; ++i) {
        int s = perm[i];
        float e = a1s[s * NH1 + hidx] + ad;
        e = (e > 0.f) ? e : 0.2f * e;
        float p = __expf(e);
        acc += p * __bfloat162float(h1[s * F1 + c]);
        den += p;
    }
    float v = acc / (den + 1e-16f) + loadF(b1, c, fp32);
    v = (v > 0.f) ? v : expm1f(v);               // ELU
    helu[d * F1 + c] = __float2bfloat16(v);
}

// ---------------- Layer 2 GEMM + attention coefficients ----------------

__global__ __launch_bounds__(256) void k_gemm2(
    const __hip_bfloat16* __restrict__ helu, const void* __restrict__ W2,
    const void* __restrict__ attS, const void* __restrict__ attD,
    __hip_bfloat16* __restrict__ h2, float* __restrict__ a2s,
    float* __restrict__ a2d, int n, const int* __restrict__ flags) {
    int fp32 = flags[0];
    __shared__ float Wl[F1 * F2];    // 16 KB
    __shared__ float hl[16 * F1];    // 4 KB
    int tid = threadIdx.x;
    for (int i = tid; i < F1 * F2; i += 256) Wl[i] = loadF(W2, i, fp32);
    int n0 = blockIdx.x * 16;
    for (int i = tid; i < 16 * F1; i += 256) {
        int node = n0 + i / F1;
        hl[i] = (node < n) ? __bfloat162float(helu[node * F1 + (i % F1)]) : 0.f;
    }
    __syncthreads();
    int w = tid >> 6, c = tid & 63;
    float aS = loadF(attS, c, fp32);
    float aD = loadF(attD, c, fp32);
    float acc[4] = {0.f, 0.f, 0.f, 0.f};
    int base = w * 4;
    #pragma unroll 4
    for (int k = 0; k < F1; ++k) {
        float wv = Wl[k * F2 + c];
        acc[0] += hl[(base + 0) * F1 + k] * wv;
        acc[1] += hl[(base + 1) * F1 + k] * wv;
        acc[2] += hl[(base + 2) * F1 + k] * wv;
        acc[3] += hl[(base + 3) * F1 + k] * wv;
    }
    for (int m = 0; m < 4; ++m) {
        int node = n0 + base + m;
        if (node >= n) break;
        float v = acc[m];
        h2[node * F2 + c] = __float2bfloat16(v);
        float ps = v * aS, pd = v * aD;
        for (int off = 1; off < 64; off <<= 1) {
            ps += __shfl_xor(ps, off, 64);
            pd += __shfl_xor(pd, off, 64);
        }
        if (c == 0) { a2s[node] = ps; a2d[node] = pd; }
    }
}

// ---------------- Layer 2 aggregation + final linear ----------------

__global__ __launch_bounds__(256) void k_agg2(
    const int* __restrict__ offs, const int* __restrict__ perm,
    const __hip_bfloat16* __restrict__ h2, const float* __restrict__ a2s,
    const float* __restrict__ a2d, const void* __restrict__ b2,
    const void* __restrict__ linW, const void* __restrict__ linb,
    void* __restrict__ out, int n, const int* __restrict__ flags) {
    int fp32 = flags[0];
    int w = threadIdx.x >> 6, c = threadIdx.x & 63;
    int d = blockIdx.x * 4 + w;
    if (d >= n) return;
    int start = offs[d], end = offs[d + 1];
    float ad = a2d[d];
    float acc = 0.f, den = 0.f;
    const unsigned short* hu = (const unsigned short*)h2;
    int i = start;
    for (; i + UNR <= end; i += UNR) {
        int ss[UNR];
        #pragma unroll
        for (int u = 0; u < UNR; ++u) ss[u] = perm[i + u];
        float ee[UNR];
        unsigned short hh[UNR];
        #pragma unroll
        for (int u = 0; u < UNR; ++u) ee[u] = a2s[ss[u]];
        #pragma unroll
        for (int u = 0; u < UNR; ++u) hh[u] = hu[ss[u] * F2 + c];
        #pragma unroll
        for (int u = 0; u < UNR; ++u) {
            float e = ee[u] + ad;
            e = (e > 0.f) ? e : 0.2f * e;
            float p = __expf(e);
            unsigned hb = ((unsigned)hh[u]) << 16;
            acc += p * __uint_as_float(hb);
            den += p;
        }
    }
    for (; i < end; ++i) {
        int s = perm[i];
        float e = a2s[s] + ad;
        e = (e > 0.f) ? e : 0.2f * e;
        float p = __expf(e);
        acc += p * __bfloat162float(h2[s * F2 + c]);
        den += p;
    }
    float v = acc / (den + 1e-16f) + loadF(b2, c, fp32);
    float part = v * loadF(linW, c, fp32);
    for (int off = 1; off < 64; off <<= 1) part += __shfl_xor(part, off, 64);
    if (c == 0) {
        float r = part + loadF(linb, 0, fp32);
        if (fp32) ((float*)out)[d] = r;
        else      ((__hip_bfloat16*)out)[d] = __float2bfloat16(r);
    }
}

// ---------------- host launcher ----------------

static inline char* carve(char*& p, size_t bytes) {
    char* r = p;
    p += (bytes + 255) & ~size_t(255);
    return r;
}

extern "C" void kernel_launch(void* const* d_in, const int* in_sizes, int n_in,
                              void* d_out, int out_size, void* d_ws, size_t ws_size,
                              hipStream_t stream) {
    const void* x     = d_in[0];
    const void* ei    = d_in[1];
    const void* W1    = d_in[2];
    const void* attS1 = d_in[3];
    const void* attD1 = d_in[4];
    const void* b1    = d_in[5];
    const void* W2    = d_in[6];
    const void* attS2 = d_in[7];
    const void* attD2 = d_in[8];
    const void* b2    = d_in[9];
    const void* linW  = d_in[10];
    const void* linb  = d_in[11];

    int E    = in_sizes[1] / 2;
    int Etot = E + NN;

    // workspace layout (~23 MB total)
    char* p = (char*)d_ws;
    int*   flags = (int*)carve(p, 256);
    int*   deg   = (int*)carve(p, (size_t)NN * 4);
    int*   offs  = (int*)carve(p, (size_t)(NN + 1) * 4);
    int*   next  = (int*)carve(p, (size_t)NN * 4);
    int*   bsum  = (int*)carve(p, 512 * 4);
    int*   perm  = (int*)carve(p, (size_t)Etot * 4);
    float* a1s   = (float*)carve(p, (size_t)NN * NH1 * 4);   // reused as a2s
    float* a1d   = (float*)carve(p, (size_t)NN * NH1 * 4);   // reused as a2d
    __hip_bfloat16* h1   = (__hip_bfloat16*)carve(p, (size_t)NN * F1 * 2); // reused as h2
    __hip_bfloat16* helu = (__hip_bfloat16*)carve(p, (size_t)NN * F1 * 2);
    float* a2s = a1s;
    float* a2d = a1d;
    __hip_bfloat16* h2 = h1;

    hipMemsetAsync(deg, 0, (size_t)NN * 4, stream);
    k_sniff<<<1, 256, 0, stream>>>(x, ei, flags);

    int eb = (Etot + 255) / 256;
    k_count<<<eb, 256, 0, stream>>>(ei, E, Etot, deg, flags);
    int nb = (NN + 511) / 512;
    k_scan_a<<<nb, 512, 0, stream>>>(deg, offs, bsum, NN);
    k_scan_b<<<1, 64, 0, stream>>>(bsum, nb);
    k_scan_c<<<nb, 512, 0, stream>>>(offs, next, bsum, NN, Etot);
    k_scatter<<<eb, 256, 0, stream>>>(ei, E, Etot, next, perm, flags);

    k_gemm1<<<(NN + 15) / 16, 256, 0, stream>>>(x, W1, attS1, attD1, h1, a1s, a1d, NN, flags);
    k_agg1<<<(NN + 3) / 4, 256, 0, stream>>>(offs, perm, h1, a1s, a1d, b1, helu, NN, flags);
    k_gemm2<<<(NN + 15) / 16, 256, 0, stream>>>(helu, W2, attS2, attD2, h2, a2s, a2d, NN, flags);
    k_agg2<<<(NN + 3) / 4, 256, 0, stream>>>(offs, perm, h2, a2s, a2d, b2, linW, linb, d_out, NN, flags);
}

// Round 4
// 475.931 us; speedup vs baseline: 1.5991x; 1.1127x over previous
//
#include <hip/hip_runtime.h>
#include <hip/hip_bf16.h>
#include <math.h>

#define NN     50000
#define FIN    128
#define F1     64      // H1*C1 = layer-1 output features
#define NH1    8
#define F2     64      // layer-2 output features
#define XCDS   8
#define NPX    ((NN + XCDS - 1) / XCDS)   // 6250 nodes per XCD partition

// ---------------- runtime dtype helpers ----------------
// flags[0] = 1 if float tensors are fp32 (else bf16)
// flags[1] = 1 if edge_index is int64 (else int32)

__device__ __forceinline__ float loadF(const void* p, long long i, int fp32) {
    if (fp32) return ((const float*)p)[i];
    return __bfloat162float(((const __hip_bfloat16*)p)[i]);
}
__device__ __forceinline__ int loadI(const void* p, long long i, int i64) {
    if (i64) return (int)((const long long*)p)[i];
    return ((const int*)p)[i];
}
// non-temporal edge-endpoint load (streaming, avoid polluting L2 write lines)
__device__ __forceinline__ int loadI_nt(const void* p, long long i, int i64) {
    if (i64) return (int)__builtin_nontemporal_load(&((const long long*)p)[i]);
    return __builtin_nontemporal_load(&((const int*)p)[i]);
}

__global__ void k_sniff(const void* x, const void* ei, int* flags) {
    __shared__ int s_nanexp, s_oddnz;
    if (threadIdx.x == 0) { s_nanexp = 0; s_oddnz = 0; }
    __syncthreads();
    const unsigned short* u = (const unsigned short*)x;
    int cnt = 0;
    for (int i = threadIdx.x; i < 8192; i += 256) {
        unsigned short v = u[i];
        if ((v & 0x7F80) == 0x7F80) cnt++;         // bf16 Inf/NaN bit pattern
    }
    if (cnt) atomicAdd(&s_nanexp, cnt);
    const unsigned* e32 = (const unsigned*)ei;
    int nz = 0;
    for (int i = threadIdx.x; i < 2048; i += 256) {
        if (e32[2 * i + 1] != 0u) nz++;            // high words if int64
    }
    if (nz) atomicAdd(&s_oddnz, nz);
    __syncthreads();
    if (threadIdx.x == 0) {
        flags[0] = (s_nanexp > 2) ? 1 : 0;         // fp32 floats
        flags[1] = (s_oddnz == 0) ? 1 : 0;         // int64 edges
    }
}

// ---------------- CSR build (XCD-partitioned by dst range) ----------------
// blockIdx%8 -> XCD (round-robin dispatch heuristic); each XCD handles nodes
// [xcd*NPX, xcd*NPX+NPX) so deg/next/perm lines are written by ONE XCD's L2
// and accumulate all their writes before eviction (R3: WRITE_SIZE was 16x
// amplified by cross-XCD random 4B stores).

#define SUNR 8

__global__ __launch_bounds__(256) void k_count(
    const void* __restrict__ ei, int E, int Etot,
    int* __restrict__ deg, const int* __restrict__ flags) {
    int i64 = flags[1];
    int xcd = blockIdx.x & 7;
    int chunk = blockIdx.x >> 3;
    int nchunks = gridDim.x >> 3;
    int lo = xcd * NPX;
    int hi = lo + NPX; if (hi > NN) hi = NN;
    long long per = ((long long)Etot + nchunks - 1) / nchunks;
    long long e0 = (long long)chunk * per;
    long long e1 = e0 + per; if (e1 > Etot) e1 = Etot;
    for (long long base = e0; base < e1; base += 256LL * SUNR) {
        int dd[SUNR];
        #pragma unroll
        for (int u = 0; u < SUNR; ++u) {
            long long j = base + (long long)u * 256 + threadIdx.x;
            int d = -1;
            if (j < e1) d = (j < E) ? loadI_nt(ei, (long long)E + j, i64) : (int)(j - E);
            dd[u] = d;
        }
        #pragma unroll
        for (int u = 0; u < SUNR; ++u)
            if (dd[u] >= lo && dd[u] < hi) atomicAdd(&deg[dd[u]], 1);
    }
}

__global__ void k_scan_a(const int* __restrict__ deg, int* __restrict__ offs,
                         int* __restrict__ bsum, int n) {
    __shared__ int sd[512];
    int tid = threadIdx.x;
    int i = blockIdx.x * 512 + tid;
    int v = (i < n) ? deg[i] : 0;
    sd[tid] = v;
    __syncthreads();
    for (int off = 1; off < 512; off <<= 1) {
        int t = (tid >= off) ? sd[tid - off] : 0;
        __syncthreads();
        sd[tid] += t;
        __syncthreads();
    }
    if (i < n) offs[i] = sd[tid] - v;               // exclusive within block
    if (tid == 511) bsum[blockIdx.x] = sd[511];     // block total
}

__global__ void k_scan_b(int* __restrict__ bsum, int nb) {
    if (threadIdx.x == 0 && blockIdx.x == 0) {
        int run = 0;
        for (int b = 0; b < nb; ++b) { int t = bsum[b]; bsum[b] = run; run += t; }
    }
}

__global__ void k_scan_c(int* __restrict__ offs, int* __restrict__ next,
                         const int* __restrict__ bsum, int n, int Etot) {
    int i = blockIdx.x * 512 + threadIdx.x;
    if (i < n) {
        int v = offs[i] + bsum[blockIdx.x];
        offs[i] = v;
        next[i] = v;                                 // scatter cursor
    }
    if (i == 0) offs[n] = Etot;
}

__global__ __launch_bounds__(256) void k_scatter(
    const void* __restrict__ ei, int E, int Etot,
    int* __restrict__ next, int* __restrict__ perm,
    const int* __restrict__ flags) {
    int i64 = flags[1];
    int xcd = blockIdx.x & 7;
    int chunk = blockIdx.x >> 3;
    int nchunks = gridDim.x >> 3;
    int lo = xcd * NPX;
    int hi = lo + NPX; if (hi > NN) hi = NN;
    long long per = ((long long)Etot + nchunks - 1) / nchunks;
    long long e0 = (long long)chunk * per;
    long long e1 = e0 + per; if (e1 > Etot) e1 = Etot;
    for (long long base = e0; base < e1; base += 256LL * SUNR) {
        int dd[SUNR]; long long jj[SUNR];
        #pragma unroll
        for (int u = 0; u < SUNR; ++u) {
            long long j = base + (long long)u * 256 + threadIdx.x;
            jj[u] = j;
            int d = -1;
            if (j < e1) d = (j < E) ? loadI_nt(ei, (long long)E + j, i64) : (int)(j - E);
            dd[u] = d;
        }
        int ss[SUNR];
        #pragma unroll
        for (int u = 0; u < SUNR; ++u) {
            if (dd[u] >= lo && dd[u] < hi)
                ss[u] = (jj[u] < E) ? loadI_nt(ei, jj[u], i64) : dd[u];
        }
        #pragma unroll
        for (int u = 0; u < SUNR; ++u) {
            if (dd[u] >= lo && dd[u] < hi) {
                int pos = atomicAdd(&next[dd[u]], 1);
                perm[pos] = ss[u];
            }
        }
    }
}

// ---------------- Layer 1 GEMM + attention coefficients ----------------
// 256 threads = 4 waves; each wave computes 4 nodes (16 nodes/block).

__global__ __launch_bounds__(256) void k_gemm1(
    const void* __restrict__ x, const void* __restrict__ W1,
    const void* __restrict__ attS, const void* __restrict__ attD,
    __hip_bfloat16* __restrict__ h1, float* __restrict__ a1s,
    float* __restrict__ a1d, int n, const int* __restrict__ flags) {
    int fp32 = flags[0];
    __shared__ float Wl[FIN * F1];   // 32 KB
    __shared__ float xl[16 * FIN];   // 8 KB
    int tid = threadIdx.x;
    for (int i = tid; i < FIN * F1; i += 256) Wl[i] = loadF(W1, i, fp32);
    int n0 = blockIdx.x * 16;
    for (int i = tid; i < 16 * FIN; i += 256) {
        int node = n0 + i / FIN;
        xl[i] = (node < n) ? loadF(x, (long long)node * FIN + (i % FIN), fp32) : 0.f;
    }
    __syncthreads();
    int w = tid >> 6, c = tid & 63;
    float aS = loadF(attS, c, fp32);
    float aD = loadF(attD, c, fp32);
    float acc[4] = {0.f, 0.f, 0.f, 0.f};
    int base = w * 4;
    #pragma unroll 4
    for (int k = 0; k < FIN; ++k) {
        float wv = Wl[k * F1 + c];
        acc[0] += xl[(base + 0) * FIN + k] * wv;
        acc[1] += xl[(base + 1) * FIN + k] * wv;
        acc[2] += xl[(base + 2) * FIN + k] * wv;
        acc[3] += xl[(base + 3) * FIN + k] * wv;
    }
    for (int m = 0; m < 4; ++m) {
        int node = n0 + base + m;
        if (node >= n) break;
        float v = acc[m];
        h1[node * F1 + c] = __float2bfloat16(v);
        float ps = v * aS, pd = v * aD;
        for (int off = 1; off < 8; off <<= 1) {
            ps += __shfl_xor(ps, off, 64);
            pd += __shfl_xor(pd, off, 64);
        }
        if ((c & 7) == 0) {
            a1s[node * NH1 + (c >> 3)] = ps;
            a1d[node * NH1 + (c >> 3)] = pd;
        }
    }
}

// ---------------- Layer 1 aggregation ----------------
// One wave per dst node, lane = channel. Edge loop unrolled x8 (R2->R3: 164->~?us).

#define UNR 8

__global__ __launch_bounds__(256) void k_agg1(
    const int* __restrict__ offs, const int* __restrict__ perm,
    const __hip_bfloat16* __restrict__ h1, const float* __restrict__ a1s,
    const float* __restrict__ a1d, const void* __restrict__ b1,
    __hip_bfloat16* __restrict__ helu, int n, const int* __restrict__ flags) {
    int fp32 = flags[0];
    int w = threadIdx.x >> 6, c = threadIdx.x & 63;
    int d = blockIdx.x * 4 + w;
    if (d >= n) return;
    int start = offs[d], end = offs[d + 1];
    int hidx = c >> 3;
    float ad = a1d[d * NH1 + hidx];
    float acc = 0.f, den = 0.f;
    const unsigned short* hu = (const unsigned short*)h1;
    int i = start;
    for (; i + UNR <= end; i += UNR) {
        int ss[UNR];
        #pragma unroll
        for (int u = 0; u < UNR; ++u) ss[u] = perm[i + u];
        float ee[UNR];
        unsigned short hh[UNR];
        #pragma unroll
        for (int u = 0; u < UNR; ++u) ee[u] = a1s[ss[u] * NH1 + hidx];
        #pragma unroll
        for (int u = 0; u < UNR; ++u) hh[u] = hu[ss[u] * F1 + c];
        #pragma unroll
        for (int u = 0; u < UNR; ++u) {
            float e = ee[u] + ad;
            e = (e > 0.f) ? e : 0.2f * e;            // leaky_relu(0.2)
            float p = __expf(e);
            unsigned hb = ((unsigned)hh[u]) << 16;
            acc += p * __uint_as_float(hb);
            den += p;
        }
    }
    for (; i < end; ++i) {
        int s = perm[i];
        float e = a1s[s * NH1 + hidx] + ad;
        e = (e > 0.f) ? e : 0.2f * e;
        float p = __expf(e);
        acc += p * __bfloat162float(h1[s * F1 + c]);
        den += p;
    }
    float v = acc / (den + 1e-16f) + loadF(b1, c, fp32);
    v = (v > 0.f) ? v : expm1f(v);               // ELU
    helu[d * F1 + c] = __float2bfloat16(v);
}

// ---------------- Layer 2 GEMM + attention coefficients ----------------

__global__ __launch_bounds__(256) void k_gemm2(
    const __hip_bfloat16* __restrict__ helu, const void* __restrict__ W2,
    const void* __restrict__ attS, const void* __restrict__ attD,
    __hip_bfloat16* __restrict__ h2, float* __restrict__ a2s,
    float* __restrict__ a2d, int n, const int* __restrict__ flags) {
    int fp32 = flags[0];
    __shared__ float Wl[F1 * F2];    // 16 KB
    __shared__ float hl[16 * F1];    // 4 KB
    int tid = threadIdx.x;
    for (int i = tid; i < F1 * F2; i += 256) Wl[i] = loadF(W2, i, fp32);
    int n0 = blockIdx.x * 16;
    for (int i = tid; i < 16 * F1; i += 256) {
        int node = n0 + i / F1;
        hl[i] = (node < n) ? __bfloat162float(helu[node * F1 + (i % F1)]) : 0.f;
    }
    __syncthreads();
    int w = tid >> 6, c = tid & 63;
    float aS = loadF(attS, c, fp32);
    float aD = loadF(attD, c, fp32);
    float acc[4] = {0.f, 0.f, 0.f, 0.f};
    int base = w * 4;
    #pragma unroll 4
    for (int k = 0; k < F1; ++k) {
        float wv = Wl[k * F2 + c];
        acc[0] += hl[(base + 0) * F1 + k] * wv;
        acc[1] += hl[(base + 1) * F1 + k] * wv;
        acc[2] += hl[(base + 2) * F1 + k] * wv;
        acc[3] += hl[(base + 3) * F1 + k] * wv;
    }
    for (int m = 0; m < 4; ++m) {
        int node = n0 + base + m;
        if (node >= n) break;
        float v = acc[m];
        h2[node * F2 + c] = __float2bfloat16(v);
        float ps = v * aS, pd = v * aD;
        for (int off = 1; off < 64; off <<= 1) {
            ps += __shfl_xor(ps, off, 64);
            pd += __shfl_xor(pd, off, 64);
        }
        if (c == 0) { a2s[node] = ps; a2d[node] = pd; }
    }
}

// ---------------- Layer 2 aggregation + final linear ----------------

__global__ __launch_bounds__(256) void k_agg2(
    const int* __restrict__ offs, const int* __restrict__ perm,
    const __hip_bfloat16* __restrict__ h2, const float* __restrict__ a2s,
    const float* __restrict__ a2d, const void* __restrict__ b2,
    const void* __restrict__ linW, const void* __restrict__ linb,
    void* __restrict__ out, int n, const int* __restrict__ flags) {
    int fp32 = flags[0];
    int w = threadIdx.x >> 6, c = threadIdx.x & 63;
    int d = blockIdx.x * 4 + w;
    if (d >= n) return;
    int start = offs[d], end = offs[d + 1];
    float ad = a2d[d];
    float acc = 0.f, den = 0.f;
    const unsigned short* hu = (const unsigned short*)h2;
    int i = start;
    for (; i + UNR <= end; i += UNR) {
        int ss[UNR];
        #pragma unroll
        for (int u = 0; u < UNR; ++u) ss[u] = perm[i + u];
        float ee[UNR];
        unsigned short hh[UNR];
        #pragma unroll
        for (int u = 0; u < UNR; ++u) ee[u] = a2s[ss[u]];
        #pragma unroll
        for (int u = 0; u < UNR; ++u) hh[u] = hu[ss[u] * F2 + c];
        #pragma unroll
        for (int u = 0; u < UNR; ++u) {
            float e = ee[u] + ad;
            e = (e > 0.f) ? e : 0.2f * e;
            float p = __expf(e);
            unsigned hb = ((unsigned)hh[u]) << 16;
            acc += p * __uint_as_float(hb);
            den += p;
        }
    }
    for (; i < end; ++i) {
        int s = perm[i];
        float e = a2s[s] + ad;
        e = (e > 0.f) ? e : 0.2f * e;
        float p = __expf(e);
        acc += p * __bfloat162float(h2[s * F2 + c]);
        den += p;
    }
    float v = acc / (den + 1e-16f) + loadF(b2, c, fp32);
    float part = v * loadF(linW, c, fp32);
    for (int off = 1; off < 64; off <<= 1) part += __shfl_xor(part, off, 64);
    if (c == 0) {
        float r = part + loadF(linb, 0, fp32);
        if (fp32) ((float*)out)[d] = r;
        else      ((__hip_bfloat16*)out)[d] = __float2bfloat16(r);
    }
}

// ---------------- host launcher ----------------

static inline char* carve(char*& p, size_t bytes) {
    char* r = p;
    p += (bytes + 255) & ~size_t(255);
    return r;
}

extern "C" void kernel_launch(void* const* d_in, const int* in_sizes, int n_in,
                              void* d_out, int out_size, void* d_ws, size_t ws_size,
                              hipStream_t stream) {
    const void* x     = d_in[0];
    const void* ei    = d_in[1];
    const void* W1    = d_in[2];
    const void* attS1 = d_in[3];
    const void* attD1 = d_in[4];
    const void* b1    = d_in[5];
    const void* W2    = d_in[6];
    const void* attS2 = d_in[7];
    const void* attD2 = d_in[8];
    const void* b2    = d_in[9];
    const void* linW  = d_in[10];
    const void* linb  = d_in[11];

    int E    = in_sizes[1] / 2;
    int Etot = E + NN;

    // workspace layout (~23 MB total)
    char* p = (char*)d_ws;
    int*   flags = (int*)carve(p, 256);
    int*   deg   = (int*)carve(p, (size_t)NN * 4);
    int*   offs  = (int*)carve(p, (size_t)(NN + 1) * 4);
    int*   next  = (int*)carve(p, (size_t)NN * 4);
    int*   bsum  = (int*)carve(p, 512 * 4);
    int*   perm  = (int*)carve(p, (size_t)Etot * 4);
    float* a1s   = (float*)carve(p, (size_t)NN * NH1 * 4);   // reused as a2s
    float* a1d   = (float*)carve(p, (size_t)NN * NH1 * 4);   // reused as a2d
    __hip_bfloat16* h1   = (__hip_bfloat16*)carve(p, (size_t)NN * F1 * 2); // reused as h2
    __hip_bfloat16* helu = (__hip_bfloat16*)carve(p, (size_t)NN * F1 * 2);
    float* a2s = a1s;
    float* a2d = a1d;
    __hip_bfloat16* h2 = h1;

    hipMemsetAsync(deg, 0, (size_t)NN * 4, stream);
    k_sniff<<<1, 256, 0, stream>>>(x, ei, flags);

    k_count<<<1024, 256, 0, stream>>>(ei, E, Etot, deg, flags);
    int nb = (NN + 511) / 512;
    k_scan_a<<<nb, 512, 0, stream>>>(deg, offs, bsum, NN);
    k_scan_b<<<1, 64, 0, stream>>>(bsum, nb);
    k_scan_c<<<nb, 512, 0, stream>>>(offs, next, bsum, NN, Etot);
    k_scatter<<<1024, 256, 0, stream>>>(ei, E, Etot, next, perm, flags);

    k_gemm1<<<(NN + 15) / 16, 256, 0, stream>>>(x, W1, attS1, attD1, h1, a1s, a1d, NN, flags);
    k_agg1<<<(NN + 3) / 4, 256, 0, stream>>>(offs, perm, h1, a1s, a1d, b1, helu, NN, flags);
    k_gemm2<<<(NN + 15) / 16, 256, 0, stream>>>(helu, W2, attS2, attD2, h2, a2s, a2d, NN, flags);
    k_agg2<<<(NN + 3) / 4, 256, 0, stream>>>(offs, perm, h2, a2s, a2d, b2, linW, linb, d_out, NN, flags);
}

// Round 5
// 468.092 us; speedup vs baseline: 1.6258x; 1.0167x over previous
//
#include <hip/hip_runtime.h>
#include <hip/hip_bf16.h>
#include <math.h>

#define NN     50000
#define FIN    128
#define F1     64      // H1*C1 = layer-1 output features
#define NH1    8
#define F2     64      // layer-2 output features
#define XCDS   8
#define NPX    ((NN + XCDS - 1) / XCDS)   // 6250 nodes per XCD partition
#define BCAP   250000                      // binned-edge capacity per bucket

// ---------------- runtime dtype helpers ----------------
// flags[0] = 1 if float tensors are fp32 (else bf16)
// flags[1] = 1 if edge_index is int64 (else int32)

__device__ __forceinline__ float loadF(const void* p, long long i, int fp32) {
    if (fp32) return ((const float*)p)[i];
    return __bfloat162float(((const __hip_bfloat16*)p)[i]);
}
__device__ __forceinline__ int loadI_nt(const void* p, long long i, int i64) {
    if (i64) return (int)__builtin_nontemporal_load(&((const long long*)p)[i]);
    return __builtin_nontemporal_load(&((const int*)p)[i]);
}

__global__ void k_sniff(const void* x, const void* ei, int* flags) {
    __shared__ int s_nanexp, s_oddnz;
    if (threadIdx.x == 0) { s_nanexp = 0; s_oddnz = 0; }
    __syncthreads();
    const unsigned short* u = (const unsigned short*)x;
    int cnt = 0;
    for (int i = threadIdx.x; i < 8192; i += 256) {
        unsigned short v = u[i];
        if ((v & 0x7F80) == 0x7F80) cnt++;         // bf16 Inf/NaN bit pattern
    }
    if (cnt) atomicAdd(&s_nanexp, cnt);
    const unsigned* e32 = (const unsigned*)ei;
    int nz = 0;
    for (int i = threadIdx.x; i < 2048; i += 256) {
        if (e32[2 * i + 1] != 0u) nz++;            // high words if int64
    }
    if (nz) atomicAdd(&s_oddnz, nz);
    __syncthreads();
    if (threadIdx.x == 0) {
        flags[0] = (s_nanexp > 2) ? 1 : 0;         // fp32 floats
        flags[1] = (s_oddnz == 0) ? 1 : 0;         // int64 edges
    }
}

// ---------------- CSR build: radix-bin by dst range, then XCD-local passes ----
// R4 showed the scan-everything-per-XCD scatter at 114 MB HBM traffic (9x
// write amplification + 8x dst re-read). Phase A reads edges ONCE, bins them
// into 8 dst-range buckets with coalesced segment writes; B1/B2 then touch
// only XCD-local data so deg/next/perm lines accumulate in the local L2.

__global__ __launch_bounds__(256) void k_bin(
    const void* __restrict__ ei, int E, int Etot,
    int* __restrict__ bcnt, uint2* __restrict__ binned,
    const int* __restrict__ flags) {
    int i64 = flags[1];
    __shared__ int hist[XCDS], gbase[XCDS];
    if (threadIdx.x < XCDS) hist[threadIdx.x] = 0;
    __syncthreads();
    long long base = (long long)blockIdx.x * 2048;
    int ss[8], dd[8];
    #pragma unroll
    for (int u = 0; u < 8; ++u) {
        long long j = base + u * 256 + threadIdx.x;
        int s = -1, d = -1;
        if (j < Etot) {
            if (j < E) { s = loadI_nt(ei, j, i64); d = loadI_nt(ei, (long long)E + j, i64); }
            else       { s = d = (int)(j - E); }
            if ((unsigned)s >= NN || (unsigned)d >= NN) { s = -1; d = -1; }
        }
        ss[u] = s; dd[u] = d;
        if (d >= 0) atomicAdd(&hist[d / NPX], 1);
    }
    __syncthreads();
    if (threadIdx.x < XCDS) {
        gbase[threadIdx.x] = atomicAdd(&bcnt[threadIdx.x], hist[threadIdx.x]);
        hist[threadIdx.x] = 0;                      // reuse as local cursor
    }
    __syncthreads();
    #pragma unroll
    for (int u = 0; u < 8; ++u) {
        if (dd[u] >= 0) {
            int bk = dd[u] / NPX;
            int pos = gbase[bk] + atomicAdd(&hist[bk], 1);
            if (pos < BCAP)
                binned[(size_t)bk * BCAP + pos] = make_uint2((unsigned)ss[u], (unsigned)dd[u]);
        }
    }
}

__global__ __launch_bounds__(256) void k_count2(
    const int* __restrict__ bcnt, const uint2* __restrict__ binned,
    int* __restrict__ deg) {
    int bk = blockIdx.x & 7, sub = blockIdx.x >> 3;
    int cnt = bcnt[bk]; if (cnt > BCAP) cnt = BCAP;
    int per = (cnt + 127) >> 7;                     // 128 sub-chunks per bucket
    int s0 = sub * per, s1 = s0 + per; if (s1 > cnt) s1 = cnt;
    const uint2* bp = binned + (size_t)bk * BCAP;
    for (int i = s0 + (int)threadIdx.x; i < s1; i += 256)
        atomicAdd(&deg[bp[i].y], 1);                // XCD-local lines
}

__global__ void k_scan_a(const int* __restrict__ deg, int* __restrict__ offs,
                         int* __restrict__ bsum, int n) {
    __shared__ int sd[512];
    int tid = threadIdx.x;
    int i = blockIdx.x * 512 + tid;
    int v = (i < n) ? deg[i] : 0;
    sd[tid] = v;
    __syncthreads();
    for (int off = 1; off < 512; off <<= 1) {
        int t = (tid >= off) ? sd[tid - off] : 0;
        __syncthreads();
        sd[tid] += t;
        __syncthreads();
    }
    if (i < n) offs[i] = sd[tid] - v;               // exclusive within block
    if (tid == 511) bsum[blockIdx.x] = sd[511];     // block total
}

__global__ void k_scan_b(int* __restrict__ bsum, int nb) {
    if (threadIdx.x == 0 && blockIdx.x == 0) {
        int run = 0;
        for (int b = 0; b < nb; ++b) { int t = bsum[b]; bsum[b] = run; run += t; }
    }
}

__global__ void k_scan_c(int* __restrict__ offs, int* __restrict__ next,
                         const int* __restrict__ bsum, int n, int Etot) {
    int i = blockIdx.x * 512 + threadIdx.x;
    if (i < n) {
        int v = offs[i] + bsum[blockIdx.x];
        offs[i] = v;
        next[i] = v;                                 // scatter cursor
    }
    if (i == 0) offs[n] = Etot;
}

__global__ __launch_bounds__(256) void k_scatter2(
    const int* __restrict__ bcnt, const uint2* __restrict__ binned,
    int* __restrict__ next, int* __restrict__ perm) {
    int bk = blockIdx.x & 7, sub = blockIdx.x >> 3;
    int cnt = bcnt[bk]; if (cnt > BCAP) cnt = BCAP;
    int per = (cnt + 127) >> 7;
    int s0 = sub * per, s1 = s0 + per; if (s1 > cnt) s1 = cnt;
    const uint2* bp = binned + (size_t)bk * BCAP;
    for (int ib = s0; ib < s1; ib += 1024) {
        uint2 ee[4]; int ok[4];
        #pragma unroll
        for (int u = 0; u < 4; ++u) {
            int i = ib + u * 256 + (int)threadIdx.x;
            ok[u] = (i < s1);
            ee[u] = ok[u] ? bp[i] : make_uint2(0, 0);
        }
        int pp[4];
        #pragma unroll
        for (int u = 0; u < 4; ++u) if (ok[u]) pp[u] = atomicAdd(&next[ee[u].y], 1);
        #pragma unroll
        for (int u = 0; u < 4; ++u) if (ok[u]) perm[pp[u]] = ee[u].x;
    }
}

// ---------------- Layer 1 GEMM + attention coefficients ----------------
// 256 threads = 4 waves; each wave computes 4 nodes (16 nodes/block).

__global__ __launch_bounds__(256) void k_gemm1(
    const void* __restrict__ x, const void* __restrict__ W1,
    const void* __restrict__ attS, const void* __restrict__ attD,
    __hip_bfloat16* __restrict__ h1, float* __restrict__ a1s,
    float* __restrict__ a1d, int n, const int* __restrict__ flags) {
    int fp32 = flags[0];
    __shared__ float Wl[FIN * F1];   // 32 KB
    __shared__ float xl[16 * FIN];   // 8 KB
    int tid = threadIdx.x;
    for (int i = tid; i < FIN * F1; i += 256) Wl[i] = loadF(W1, i, fp32);
    int n0 = blockIdx.x * 16;
    for (int i = tid; i < 16 * FIN; i += 256) {
        int node = n0 + i / FIN;
        xl[i] = (node < n) ? loadF(x, (long long)node * FIN + (i % FIN), fp32) : 0.f;
    }
    __syncthreads();
    int w = tid >> 6, c = tid & 63;
    float aS = loadF(attS, c, fp32);
    float aD = loadF(attD, c, fp32);
    float acc[4] = {0.f, 0.f, 0.f, 0.f};
    int base = w * 4;
    #pragma unroll 4
    for (int k = 0; k < FIN; ++k) {
        float wv = Wl[k * F1 + c];
        acc[0] += xl[(base + 0) * FIN + k] * wv;
        acc[1] += xl[(base + 1) * FIN + k] * wv;
        acc[2] += xl[(base + 2) * FIN + k] * wv;
        acc[3] += xl[(base + 3) * FIN + k] * wv;
    }
    for (int m = 0; m < 4; ++m) {
        int node = n0 + base + m;
        if (node >= n) break;
        float v = acc[m];
        h1[node * F1 + c] = __float2bfloat16(v);
        float ps = v * aS, pd = v * aD;
        for (int off = 1; off < 8; off <<= 1) {
            ps += __shfl_xor(ps, off, 64);
            pd += __shfl_xor(pd, off, 64);
        }
        if ((c & 7) == 0) {
            a1s[node * NH1 + (c >> 3)] = ps;
            a1d[node * NH1 + (c >> 3)] = pd;
        }
    }
}

// ---------------- Layer 1 aggregation ----------------
// One wave per dst node, lane = channel. Edge loop unrolled x8 (R2->R3 win).

#define UNR 8

__global__ __launch_bounds__(256) void k_agg1(
    const int* __restrict__ offs, const int* __restrict__ perm,
    const __hip_bfloat16* __restrict__ h1, const float* __restrict__ a1s,
    const float* __restrict__ a1d, const void* __restrict__ b1,
    __hip_bfloat16* __restrict__ helu, int n, const int* __restrict__ flags) {
    int fp32 = flags[0];
    int w = threadIdx.x >> 6, c = threadIdx.x & 63;
    int d = blockIdx.x * 4 + w;
    if (d >= n) return;
    int start = offs[d], end = offs[d + 1];
    int hidx = c >> 3;
    float ad = a1d[d * NH1 + hidx];
    float acc = 0.f, den = 0.f;
    const unsigned short* hu = (const unsigned short*)h1;
    int i = start;
    for (; i + UNR <= end; i += UNR) {
        int ss[UNR];
        #pragma unroll
        for (int u = 0; u < UNR; ++u) ss[u] = perm[i + u];
        float ee[UNR];
        unsigned short hh[UNR];
        #pragma unroll
        for (int u = 0; u < UNR; ++u) ee[u] = a1s[ss[u] * NH1 + hidx];
        #pragma unroll
        for (int u = 0; u < UNR; ++u) hh[u] = hu[ss[u] * F1 + c];
        #pragma unroll
        for (int u = 0; u < UNR; ++u) {
            float e = ee[u] + ad;
            e = (e > 0.f) ? e : 0.2f * e;            // leaky_relu(0.2)
            float p = __expf(e);
            unsigned hb = ((unsigned)hh[u]) << 16;
            acc += p * __uint_as_float(hb);
            den += p;
        }
    }
    for (; i < end; ++i) {
        int s = perm[i];
        float e = a1s[s * NH1 + hidx] + ad;
        e = (e > 0.f) ? e : 0.2f * e;
        float p = __expf(e);
        acc += p * __bfloat162float(h1[s * F1 + c]);
        den += p;
    }
    float v = acc / (den + 1e-16f) + loadF(b1, c, fp32);
    v = (v > 0.f) ? v : expm1f(v);               // ELU
    helu[d * F1 + c] = __float2bfloat16(v);
}

// ---------------- Layer 2 GEMM + attention coefficients ----------------

__global__ __launch_bounds__(256) void k_gemm2(
    const __hip_bfloat16* __restrict__ helu, const void* __restrict__ W2,
    const void* __restrict__ attS, const void* __restrict__ attD,
    __hip_bfloat16* __restrict__ h2, float* __restrict__ a2s,
    float* __restrict__ a2d, int n, const int* __restrict__ flags) {
    int fp32 = flags[0];
    __shared__ float Wl[F1 * F2];    // 16 KB
    __shared__ float hl[16 * F1];    // 4 KB
    int tid = threadIdx.x;
    for (int i = tid; i < F1 * F2; i += 256) Wl[i] = loadF(W2, i, fp32);
    int n0 = blockIdx.x * 16;
    for (int i = tid; i < 16 * F1; i += 256) {
        int node = n0 + i / F1;
        hl[i] = (node < n) ? __bfloat162float(helu[node * F1 + (i % F1)]) : 0.f;
    }
    __syncthreads();
    int w = tid >> 6, c = tid & 63;
    float aS = loadF(attS, c, fp32);
    float aD = loadF(attD, c, fp32);
    float acc[4] = {0.f, 0.f, 0.f, 0.f};
    int base = w * 4;
    #pragma unroll 4
    for (int k = 0; k < F1; ++k) {
        float wv = Wl[k * F2 + c];
        acc[0] += hl[(base + 0) * F1 + k] * wv;
        acc[1] += hl[(base + 1) * F1 + k] * wv;
        acc[2] += hl[(base + 2) * F1 + k] * wv;
        acc[3] += hl[(base + 3) * F1 + k] * wv;
    }
    for (int m = 0; m < 4; ++m) {
        int node = n0 + base + m;
        if (node >= n) break;
        float v = acc[m];
        h2[node * F2 + c] = __float2bfloat16(v);
        float ps = v * aS, pd = v * aD;
        for (int off = 1; off < 64; off <<= 1) {
            ps += __shfl_xor(ps, off, 64);
            pd += __shfl_xor(pd, off, 64);
        }
        if (c == 0) { a2s[node] = ps; a2d[node] = pd; }
    }
}

// ---------------- Layer 2 aggregation + final linear ----------------

__global__ __launch_bounds__(256) void k_agg2(
    const int* __restrict__ offs, const int* __restrict__ perm,
    const __hip_bfloat16* __restrict__ h2, const float* __restrict__ a2s,
    const float* __restrict__ a2d, const void* __restrict__ b2,
    const void* __restrict__ linW, const void* __restrict__ linb,
    void* __restrict__ out, int n, const int* __restrict__ flags) {
    int fp32 = flags[0];
    int w = threadIdx.x >> 6, c = threadIdx.x & 63;
    int d = blockIdx.x * 4 + w;
    if (d >= n) return;
    int start = offs[d], end = offs[d + 1];
    float ad = a2d[d];
    float acc = 0.f, den = 0.f;
    const unsigned short* hu = (const unsigned short*)h2;
    int i = start;
    for (; i + UNR <= end; i += UNR) {
        int ss[UNR];
        #pragma unroll
        for (int u = 0; u < UNR; ++u) ss[u] = perm[i + u];
        float ee[UNR];
        unsigned short hh[UNR];
        #pragma unroll
        for (int u = 0; u < UNR; ++u) ee[u] = a2s[ss[u]];
        #pragma unroll
        for (int u = 0; u < UNR; ++u) hh[u] = hu[ss[u] * F2 + c];
        #pragma unroll
        for (int u = 0; u < UNR; ++u) {
            float e = ee[u] + ad;
            e = (e > 0.f) ? e : 0.2f * e;
            float p = __expf(e);
            unsigned hb = ((unsigned)hh[u]) << 16;
            acc += p * __uint_as_float(hb);
            den += p;
        }
    }
    for (; i < end; ++i) {
        int s = perm[i];
        float e = a2s[s] + ad;
        e = (e > 0.f) ? e : 0.2f * e;
        float p = __expf(e);
        acc += p * __bfloat162float(h2[s * F2 + c]);
        den += p;
    }
    float v = acc / (den + 1e-16f) + loadF(b2, c, fp32);
    float part = v * loadF(linW, c, fp32);
    for (int off = 1; off < 64; off <<= 1) part += __shfl_xor(part, off, 64);
    if (c == 0) {
        float r = part + loadF(linb, 0, fp32);
        if (fp32) ((float*)out)[d] = r;
        else      ((__hip_bfloat16*)out)[d] = __float2bfloat16(r);
    }
}

// ---------------- host launcher ----------------

static inline char* carve(char*& p, size_t bytes) {
    char* r = p;
    p += (bytes + 255) & ~size_t(255);
    return r;
}

extern "C" void kernel_launch(void* const* d_in, const int* in_sizes, int n_in,
                              void* d_out, int out_size, void* d_ws, size_t ws_size,
                              hipStream_t stream) {
    const void* x     = d_in[0];
    const void* ei    = d_in[1];
    const void* W1    = d_in[2];
    const void* attS1 = d_in[3];
    const void* attD1 = d_in[4];
    const void* b1    = d_in[5];
    const void* W2    = d_in[6];
    const void* attS2 = d_in[7];
    const void* attD2 = d_in[8];
    const void* b2    = d_in[9];
    const void* linW  = d_in[10];
    const void* linb  = d_in[11];

    int E    = in_sizes[1] / 2;
    int Etot = E + NN;

    // workspace layout (~23 MB total)
    char* p = (char*)d_ws;
    int*   flags = (int*)carve(p, 256);
    int*   bcnt  = (int*)carve(p, 256);               // 8 bucket cursors
    int*   deg   = (int*)carve(p, (size_t)NN * 4);
    int*   offs  = (int*)carve(p, (size_t)(NN + 1) * 4);
    int*   next  = (int*)carve(p, (size_t)NN * 4);
    int*   bsum  = (int*)carve(p, 512 * 4);
    int*   perm  = (int*)carve(p, (size_t)Etot * 4);
    // 16 MB "big" region: a1s/a1d/h1/helu for compute, aliased by the binned
    // edge buffer (8 buckets x 250k x 8B = 16 MB) which is dead before gemm1.
    char*  big   = carve(p, 16000000);
    float* a1s   = (float*)big;                                    // 1.6 MB
    float* a1d   = (float*)(big + 1600000);                        // 1.6 MB
    __hip_bfloat16* h1   = (__hip_bfloat16*)(big + 3200000);       // 6.4 MB
    __hip_bfloat16* helu = (__hip_bfloat16*)(big + 9600000);       // 6.4 MB
    uint2* binned = (uint2*)big;
    float* a2s = a1s;
    float* a2d = a1d;
    __hip_bfloat16* h2 = h1;

    // bcnt + deg are adjacent 256B-aligned carves — zero both in one call
    hipMemsetAsync(bcnt, 0, 256 + (size_t)NN * 4, stream);
    k_sniff<<<1, 256, 0, stream>>>(x, ei, flags);

    int ab = (Etot + 2047) / 2048;
    k_bin<<<ab, 256, 0, stream>>>(ei, E, Etot, bcnt, binned, flags);
    k_count2<<<1024, 256, 0, stream>>>(bcnt, binned, deg);
    int nb = (NN + 511) / 512;
    k_scan_a<<<nb, 512, 0, stream>>>(deg, offs, bsum, NN);
    k_scan_b<<<1, 64, 0, stream>>>(bsum, nb);
    k_scan_c<<<nb, 512, 0, stream>>>(offs, next, bsum, NN, Etot);
    k_scatter2<<<1024, 256, 0, stream>>>(bcnt, binned, next, perm);

    k_gemm1<<<(NN + 15) / 16, 256, 0, stream>>>(x, W1, attS1, attD1, h1, a1s, a1d, NN, flags);
    k_agg1<<<(NN + 3) / 4, 256, 0, stream>>>(offs, perm, h1, a1s, a1d, b1, helu, NN, flags);
    k_gemm2<<<(NN + 15) / 16, 256, 0, stream>>>(helu, W2, attS2, attD2, h2, a2s, a2d, NN, flags);
    k_agg2<<<(NN + 3) / 4, 256, 0, stream>>>(offs, perm, h2, a2s, a2d, b2, linW, linb, d_out, NN, flags);
}